// Round 1
// baseline (471.677 us; speedup 1.0000x reference)
//
#include <hip/hip_runtime.h>
#include <math.h>

typedef unsigned short u16;
typedef __attribute__((ext_vector_type(4))) float f32x4;
typedef __attribute__((ext_vector_type(4))) unsigned short u16x4;
typedef __attribute__((ext_vector_type(8))) __bf16 bf16x8;

static constexpr int SS   = 2048;   // seq len
static constexpr int DD   = 1024;   // model dim
static constexpr int HH   = 16;     // heads
static constexpr int DH   = 64;     // head dim
static constexpr int NTOK = 4096;   // B*S
static constexpr int NQKV = 3072;

#define DEV static __device__ __forceinline__

DEV u16 f2bf(float f) {
    union { float f; unsigned int i; } v; v.f = f;
    unsigned int r = v.i + 0x7fffu + ((v.i >> 16) & 1u);
    return (u16)(r >> 16);
}

DEV f32x4 MFMA(bf16x8 a, bf16x8 b, f32x4 c) {
    return __builtin_amdgcn_mfma_f32_16x16x32_bf16(a, b, c, 0, 0, 0);
}

// ---------------- transpose fp32 [R][C] -> bf16 [C][R] ----------------
__global__ __launch_bounds__(256)
void k_transpose(const float* __restrict__ in, u16* __restrict__ out, int R, int C) {
    __shared__ float tile[32][33];
    int c0 = blockIdx.x * 32, r0 = blockIdx.y * 32;
    int tx = threadIdx.x, ty = threadIdx.y; // 32 x 8
    #pragma unroll
    for (int i = 0; i < 32; i += 8)
        tile[ty + i][tx] = in[(size_t)(r0 + ty + i) * C + c0 + tx];
    __syncthreads();
    #pragma unroll
    for (int i = 0; i < 32; i += 8)
        out[(size_t)(c0 + ty + i) * R + r0 + tx] = f2bf(tile[tx][ty + i]);
}

// ---------------- layernorm fp32 -> bf16, one block per row ----------------
__global__ __launch_bounds__(256)
void k_layernorm(const float* __restrict__ x, const float* __restrict__ g,
                 const float* __restrict__ b, u16* __restrict__ out) {
    int row = blockIdx.x, t = threadIdx.x;
    const float4* xp = reinterpret_cast<const float4*>(x + (size_t)row * DD);
    float4 v = xp[t];
    float s = v.x + v.y + v.z + v.w;
    float q = v.x * v.x + v.y * v.y + v.z * v.z + v.w * v.w;
    #pragma unroll
    for (int m = 1; m < 64; m <<= 1) { s += __shfl_xor(s, m); q += __shfl_xor(q, m); }
    __shared__ float ps[4], pq[4];
    int w = t >> 6, l = t & 63;
    if (l == 0) { ps[w] = s; pq[w] = q; }
    __syncthreads();
    s = ps[0] + ps[1] + ps[2] + ps[3];
    q = pq[0] + pq[1] + pq[2] + pq[3];
    float mu = s * (1.0f / DD);
    float var = q * (1.0f / DD) - mu * mu;
    float rstd = rsqrtf(var + 1e-5f);
    float4 gv = reinterpret_cast<const float4*>(g)[t];
    float4 bv = reinterpret_cast<const float4*>(b)[t];
    u16x4 o;
    o.x = f2bf((v.x - mu) * rstd * gv.x + bv.x);
    o.y = f2bf((v.y - mu) * rstd * gv.y + bv.y);
    o.z = f2bf((v.z - mu) * rstd * gv.z + bv.z);
    o.w = f2bf((v.w - mu) * rstd * gv.w + bv.w);
    reinterpret_cast<u16x4*>(out + (size_t)row * DD)[t] = o;
}

// ---------------- GEMM: C[M,N] = A[M,K](bf16) @ BT[N,K](bf16)^T ----------------
// MODE 0: qkv split -> Cb (cols<2048), vT[b][h][d][s] (cols>=2048)
// MODE 1: Cf = acc + bias[n] + res[m*N+n]   (fp32 out)
// MODE 2: Cb = bf16( gelu(acc + bias[n]) )
template<int MODE>
__global__ __launch_bounds__(256)
void k_gemm(const u16* __restrict__ A, const u16* __restrict__ BT,
            float* __restrict__ Cf, u16* __restrict__ Cb,
            const float* __restrict__ bias, const float* __restrict__ res,
            u16* __restrict__ vT, int M, int N, int K) {
    __shared__ __align__(128) char lds[32768];
    char* Al = lds;
    char* Bl = lds + 16384;
    const int t = threadIdx.x;
    const int w = t >> 6, l = t & 63;
    const int lg = l >> 4, lr = l & 15;
    const int m0 = blockIdx.y * 128, n0 = blockIdx.x * 128;
    const int wr = w >> 1, wc = w & 1;

    f32x4 acc[4][4];
    #pragma unroll
    for (int i = 0; i < 4; i++)
        #pragma unroll
        for (int j = 0; j < 4; j++)
            acc[i][j] = (f32x4){0.f, 0.f, 0.f, 0.f};

    for (int kt = 0; kt < K; kt += 64) {
        __syncthreads();
        // stage A and B tiles (128x64 bf16 each), swizzled LDS layout
        #pragma unroll
        for (int c = 0; c < 4; c++) {
            int j  = c * 256 + t;          // chunk id 0..1023
            int r  = j >> 3;               // tile row 0..127
            int cb = (j & 7) << 4;         // byte column 0..112
            int pb = r * 128 + (cb ^ ((r & 7) << 4));
            const u16* ga = A  + (size_t)(m0 + r) * K + kt + (cb >> 1);
            const u16* gb = BT + (size_t)(n0 + r) * K + kt + (cb >> 1);
            *reinterpret_cast<bf16x8*>(Al + pb) = *reinterpret_cast<const bf16x8*>(ga);
            *reinterpret_cast<bf16x8*>(Bl + pb) = *reinterpret_cast<const bf16x8*>(gb);
        }
        __syncthreads();
        #pragma unroll
        for (int s = 0; s < 2; s++) {
            const int swz = (s * 64 + lg * 16) ^ ((lr & 7) << 4);
            bf16x8 af[4], bfr[4];
            #pragma unroll
            for (int mi = 0; mi < 4; mi++)
                af[mi] = *reinterpret_cast<const bf16x8*>(Al + (wr * 64 + mi * 16 + lr) * 128 + swz);
            #pragma unroll
            for (int ni = 0; ni < 4; ni++)
                bfr[ni] = *reinterpret_cast<const bf16x8*>(Bl + (wc * 64 + ni * 16 + lr) * 128 + swz);
            #pragma unroll
            for (int mi = 0; mi < 4; mi++)
                #pragma unroll
                for (int ni = 0; ni < 4; ni++)
                    acc[mi][ni] = MFMA(af[mi], bfr[ni], acc[mi][ni]);
        }
    }

    // epilogue
    #pragma unroll
    for (int mi = 0; mi < 4; mi++) {
        #pragma unroll
        for (int ni = 0; ni < 4; ni++) {
            int nn = n0 + wc * 64 + ni * 16 + lr;
            #pragma unroll
            for (int r = 0; r < 4; r++) {
                int mm = m0 + wr * 64 + mi * 16 + lg * 4 + r;
                float v = acc[mi][ni][r];
                if (MODE == 0) {
                    if (nn < 2048) {
                        Cb[(size_t)mm * NQKV + nn] = f2bf(v);
                    } else {
                        int b = mm >> 11, sIdx = mm & 2047;
                        int hd = nn - 2048;
                        vT[(((size_t)(b * HH + (hd >> 6)) * DH) + (hd & 63)) * SS + sIdx] = f2bf(v);
                    }
                } else if (MODE == 1) {
                    Cf[(size_t)mm * N + nn] = v + bias[nn] + res[(size_t)mm * N + nn];
                } else {
                    float u = v + bias[nn];
                    float gl = 0.5f * u * (1.0f + erff(u * 0.70710678118654752f));
                    Cb[(size_t)mm * N + nn] = f2bf(gl);
                }
            }
        }
    }
}

// ---------------- flash attention: 1 wave = 16 q rows ----------------
__global__ __launch_bounds__(256)
void k_attn(const u16* __restrict__ qkv, const u16* __restrict__ vT,
            u16* __restrict__ out) {
    const int w = threadIdx.x >> 6, l = threadIdx.x & 63;
    const int lg = l >> 4, lr = l & 15;
    const int task = blockIdx.x * 4 + w;     // 0..4095
    const int bh = task >> 7;                // 0..31
    const int q16 = task & 127;
    const int b = bh >> 4, h = bh & 15;
    const size_t rowbase = (size_t)b * SS;
    const int q0 = q16 * 16;

    __shared__ __align__(16) u16 Plds_all[4][16 * 56];
    u16* Plds = Plds_all[w];

    // Q fragments (hoisted): Q[q0+lr][h*64 + s*32 + 8*lg + i]
    const u16* qrow = qkv + (rowbase + q0 + lr) * NQKV + h * DH;
    bf16x8 qf[2];
    qf[0] = *reinterpret_cast<const bf16x8*>(qrow + (lg << 3));
    qf[1] = *reinterpret_cast<const bf16x8*>(qrow + 32 + (lg << 3));

    f32x4 o[4];
    #pragma unroll
    for (int c = 0; c < 4; c++) o[c] = (f32x4){0.f, 0.f, 0.f, 0.f};
    float mrow[4], lrow[4];
    #pragma unroll
    for (int r = 0; r < 4; r++) { mrow[r] = -1e30f; lrow[r] = 0.f; }

    const u16* kbase = qkv + rowbase * NQKV + 1024 + h * DH;
    const u16* vbase = vT + (size_t)bh * DH * SS;

    for (int kv0 = 0; kv0 < SS; kv0 += 32) {
        // K fragments: rows kv0+half*16+lr, cols s*32+8*lg..+7
        bf16x8 kf[2][2];
        #pragma unroll
        for (int half = 0; half < 2; half++) {
            const u16* kr = kbase + (size_t)(kv0 + half * 16 + lr) * NQKV;
            kf[half][0] = *reinterpret_cast<const bf16x8*>(kr + (lg << 3));
            kf[half][1] = *reinterpret_cast<const bf16x8*>(kr + 32 + (lg << 3));
        }
        f32x4 s0 = (f32x4){0.f, 0.f, 0.f, 0.f};
        f32x4 s1 = (f32x4){0.f, 0.f, 0.f, 0.f};
        s0 = MFMA(qf[0], kf[0][0], s0); s0 = MFMA(qf[1], kf[0][1], s0);
        s1 = MFMA(qf[0], kf[1][0], s1); s1 = MFMA(qf[1], kf[1][1], s1);

        float sc0[4], sc1[4], scale[4], p0[4], p1[4];
        #pragma unroll
        for (int r = 0; r < 4; r++) { sc0[r] = s0[r] * 0.125f; sc1[r] = s1[r] * 0.125f; }
        #pragma unroll
        for (int r = 0; r < 4; r++) {
            float m_ = fmaxf(sc0[r], sc1[r]);
            m_ = fmaxf(m_, __shfl_xor(m_, 1));
            m_ = fmaxf(m_, __shfl_xor(m_, 2));
            m_ = fmaxf(m_, __shfl_xor(m_, 4));
            m_ = fmaxf(m_, __shfl_xor(m_, 8));
            float mn = fmaxf(mrow[r], m_);
            scale[r] = __expf(mrow[r] - mn);
            mrow[r] = mn;
            p0[r] = __expf(sc0[r] - mn);
            p1[r] = __expf(sc1[r] - mn);
            float ts = p0[r] + p1[r];
            ts += __shfl_xor(ts, 1); ts += __shfl_xor(ts, 2);
            ts += __shfl_xor(ts, 4); ts += __shfl_xor(ts, 8);
            lrow[r] = lrow[r] * scale[r] + ts;
        }
        // write P (bf16) to per-wave LDS: P[q=4*lg+r][kv]
        #pragma unroll
        for (int r = 0; r < 4; r++) {
            int q = 4 * lg + r;
            Plds[q * 56 + lr]      = f2bf(p0[r]);
            Plds[q * 56 + 16 + lr] = f2bf(p1[r]);
        }
        // rescale O
        #pragma unroll
        for (int c = 0; c < 4; c++)
            #pragma unroll
            for (int r = 0; r < 4; r++) o[c][r] *= scale[r];
        // P A-fragment: P[q=lr][kv=8*lg+i]
        bf16x8 pf = *reinterpret_cast<const bf16x8*>(&Plds[lr * 56 + (lg << 3)]);
        // V fragments from vT[b][h][d][s]: V[kv=8*lg+i][d=16c+lr]
        #pragma unroll
        for (int c = 0; c < 4; c++) {
            const u16* vr = vbase + (size_t)(c * 16 + lr) * SS + kv0 + (lg << 3);
            bf16x8 vf = *reinterpret_cast<const bf16x8*>(vr);
            o[c] = MFMA(pf, vf, o[c]);
        }
    }
    #pragma unroll
    for (int c = 0; c < 4; c++) {
        #pragma unroll
        for (int r = 0; r < 4; r++) {
            float v = o[c][r] / lrow[r];
            int q = q0 + 4 * lg + r;
            out[(rowbase + q) * DD + h * DH + c * 16 + lr] = f2bf(v);
        }
    }
}

extern "C" void kernel_launch(void* const* d_in, const int* in_sizes, int n_in,
                              void* d_out, int out_size, void* d_ws, size_t ws_size,
                              hipStream_t stream) {
    (void)in_sizes; (void)n_in; (void)out_size; (void)ws_size;
    const float* x     = (const float*)d_in[0];
    const float* w_qkv = (const float*)d_in[1];
    const float* w_out = (const float*)d_in[2];
    const float* b_out = (const float*)d_in[3];
    const float* g1    = (const float*)d_in[4];
    const float* be1   = (const float*)d_in[5];
    const float* g2    = (const float*)d_in[6];
    const float* be2   = (const float*)d_in[7];
    const float* w_ff1 = (const float*)d_in[8];
    const float* b_ff1 = (const float*)d_in[9];
    const float* w_ff2 = (const float*)d_in[10];
    const float* b_ff2 = (const float*)d_in[11];

    char* ws = (char*)d_ws;
    u16*   W  = (u16*)(ws);                  //  8.39 MB  (weight^T scratch, reused)
    u16*   Hb = (u16*)(ws + 8388608);        //  8.39 MB  (LN output bf16)
    u16*   QF = (u16*)(ws + 16777216);       // 33.55 MB  (qkv, later ffn act)
    u16*   VT = (u16*)(ws + 50331648);       //  8.39 MB  (v transposed)
    u16*   AO = (u16*)(ws + 58720256);       //  8.39 MB  (attn out bf16)
    float* X1 = (float*)(ws + 67108864);     // 16.78 MB  (post-attn residual fp32)
    float* OUT = (float*)d_out;

    // LN1: x -> Hb
    k_layernorm<<<NTOK, 256, 0, stream>>>(x, g1, be1, Hb);
    // w_qkv^T
    k_transpose<<<dim3(3072 / 32, 1024 / 32), dim3(32, 8), 0, stream>>>(w_qkv, W, 1024, 3072);
    // qkv = Hb @ w_qkv   (v written transposed to VT)
    k_gemm<0><<<dim3(3072 / 128, 4096 / 128), 256, 0, stream>>>(
        Hb, W, nullptr, QF, nullptr, nullptr, VT, NTOK, NQKV, 1024);
    // attention
    k_attn<<<1024, 256, 0, stream>>>(QF, VT, AO);
    // w_out^T
    k_transpose<<<dim3(1024 / 32, 1024 / 32), dim3(32, 8), 0, stream>>>(w_out, W, 1024, 1024);
    // X1 = x + AO @ w_out + b_out
    k_gemm<1><<<dim3(1024 / 128, 4096 / 128), 256, 0, stream>>>(
        AO, W, X1, nullptr, b_out, x, nullptr, NTOK, 1024, 1024);
    // LN2: X1 -> Hb
    k_layernorm<<<NTOK, 256, 0, stream>>>(X1, g2, be2, Hb);
    // w_ff1^T
    k_transpose<<<dim3(4096 / 32, 1024 / 32), dim3(32, 8), 0, stream>>>(w_ff1, W, 1024, 4096);
    // FFA = gelu(Hb @ w_ff1 + b_ff1)  (into QF region)
    k_gemm<2><<<dim3(4096 / 128, 4096 / 128), 256, 0, stream>>>(
        Hb, W, nullptr, QF, b_ff1, nullptr, nullptr, NTOK, 4096, 1024);
    // w_ff2^T
    k_transpose<<<dim3(1024 / 32, 4096 / 32), dim3(32, 8), 0, stream>>>(w_ff2, W, 4096, 1024);
    // OUT = X1 + FFA @ w_ff2 + b_ff2
    k_gemm<1><<<dim3(1024 / 128, 4096 / 128), 256, 0, stream>>>(
        QF, W, OUT, nullptr, b_ff2, X1, nullptr, NTOK, 1024, 4096);
}

// Round 2
// 358.877 us; speedup vs baseline: 1.3143x; 1.3143x over previous
//
#include <hip/hip_runtime.h>
#include <math.h>

typedef unsigned short u16;
typedef __attribute__((ext_vector_type(4))) float f32x4;
typedef __attribute__((ext_vector_type(16))) float f32x16;
typedef __attribute__((ext_vector_type(4))) unsigned short u16x4;
typedef __attribute__((ext_vector_type(8))) __bf16 bf16x8;

static constexpr int SS   = 2048;   // seq len
static constexpr int DD   = 1024;   // model dim
static constexpr int HH   = 16;     // heads
static constexpr int DH   = 64;     // head dim
static constexpr int NTOK = 4096;   // B*S
static constexpr int NQKV = 3072;

#define DEV static __device__ __forceinline__

DEV u16 f2bf(float f) {
    union { float f; unsigned int i; } v; v.f = f;
    unsigned int r = v.i + 0x7fffu + ((v.i >> 16) & 1u);
    return (u16)(r >> 16);
}

DEV f32x4 MFMA(bf16x8 a, bf16x8 b, f32x4 c) {
    return __builtin_amdgcn_mfma_f32_16x16x32_bf16(a, b, c, 0, 0, 0);
}
DEV f32x16 MFMA32(bf16x8 a, bf16x8 b, f32x16 c) {
    return __builtin_amdgcn_mfma_f32_32x32x16_bf16(a, b, c, 0, 0, 0);
}
DEV f32x16 zero16() {
    f32x16 z;
    #pragma unroll
    for (int i = 0; i < 16; i++) z[i] = 0.f;
    return z;
}

// ---------------- transpose fp32 [R][C] -> bf16 [C][R] ----------------
__global__ __launch_bounds__(256)
void k_transpose(const float* __restrict__ in, u16* __restrict__ out, int R, int C) {
    __shared__ float tile[32][33];
    int c0 = blockIdx.x * 32, r0 = blockIdx.y * 32;
    int tx = threadIdx.x, ty = threadIdx.y; // 32 x 8
    #pragma unroll
    for (int i = 0; i < 32; i += 8)
        tile[ty + i][tx] = in[(size_t)(r0 + ty + i) * C + c0 + tx];
    __syncthreads();
    #pragma unroll
    for (int i = 0; i < 32; i += 8)
        out[(size_t)(c0 + ty + i) * R + r0 + tx] = f2bf(tile[tx][ty + i]);
}

// ---------------- layernorm fp32 -> bf16, one block per row ----------------
__global__ __launch_bounds__(256)
void k_layernorm(const float* __restrict__ x, const float* __restrict__ g,
                 const float* __restrict__ b, u16* __restrict__ out) {
    int row = blockIdx.x, t = threadIdx.x;
    const float4* xp = reinterpret_cast<const float4*>(x + (size_t)row * DD);
    float4 v = xp[t];
    float s = v.x + v.y + v.z + v.w;
    float q = v.x * v.x + v.y * v.y + v.z * v.z + v.w * v.w;
    #pragma unroll
    for (int m = 1; m < 64; m <<= 1) { s += __shfl_xor(s, m); q += __shfl_xor(q, m); }
    __shared__ float ps[4], pq[4];
    int w = t >> 6, l = t & 63;
    if (l == 0) { ps[w] = s; pq[w] = q; }
    __syncthreads();
    s = ps[0] + ps[1] + ps[2] + ps[3];
    q = pq[0] + pq[1] + pq[2] + pq[3];
    float mu = s * (1.0f / DD);
    float var = q * (1.0f / DD) - mu * mu;
    float rstd = rsqrtf(var + 1e-5f);
    float4 gv = reinterpret_cast<const float4*>(g)[t];
    float4 bv = reinterpret_cast<const float4*>(b)[t];
    u16x4 o;
    o.x = f2bf((v.x - mu) * rstd * gv.x + bv.x);
    o.y = f2bf((v.y - mu) * rstd * gv.y + bv.y);
    o.z = f2bf((v.z - mu) * rstd * gv.z + bv.z);
    o.w = f2bf((v.w - mu) * rstd * gv.w + bv.w);
    reinterpret_cast<u16x4*>(out + (size_t)row * DD)[t] = o;
}

// ---------------- GEMM: C[M,N] = A[M,K](bf16) @ BT[N,K](bf16)^T ----------------
// MODE 0: qkv split -> Cb (cols<2048), vT[b][h][d][s] (cols>=2048)
// MODE 1: Cf = acc + bias[n] + res[m*N+n]   (fp32 out)
// MODE 2: Cb = bf16( gelu(acc + bias[n]) )
template<int MODE>
__global__ __launch_bounds__(256)
void k_gemm(const u16* __restrict__ A, const u16* __restrict__ BT,
            float* __restrict__ Cf, u16* __restrict__ Cb,
            const float* __restrict__ bias, const float* __restrict__ res,
            u16* __restrict__ vT, int M, int N, int K) {
    __shared__ __align__(128) char lds[32768];
    char* Al = lds;
    char* Bl = lds + 16384;
    const int t = threadIdx.x;
    const int w = t >> 6, l = t & 63;
    const int lg = l >> 4, lr = l & 15;
    const int m0 = blockIdx.y * 128, n0 = blockIdx.x * 128;
    const int wr = w >> 1, wc = w & 1;

    f32x4 acc[4][4];
    #pragma unroll
    for (int i = 0; i < 4; i++)
        #pragma unroll
        for (int j = 0; j < 4; j++)
            acc[i][j] = (f32x4){0.f, 0.f, 0.f, 0.f};

    for (int kt = 0; kt < K; kt += 64) {
        __syncthreads();
        // stage A and B tiles (128x64 bf16 each), swizzled LDS layout
        #pragma unroll
        for (int c = 0; c < 4; c++) {
            int j  = c * 256 + t;          // chunk id 0..1023
            int r  = j >> 3;               // tile row 0..127
            int cb = (j & 7) << 4;         // byte column 0..112
            int pb = r * 128 + (cb ^ ((r & 7) << 4));
            const u16* ga = A  + (size_t)(m0 + r) * K + kt + (cb >> 1);
            const u16* gb = BT + (size_t)(n0 + r) * K + kt + (cb >> 1);
            *reinterpret_cast<bf16x8*>(Al + pb) = *reinterpret_cast<const bf16x8*>(ga);
            *reinterpret_cast<bf16x8*>(Bl + pb) = *reinterpret_cast<const bf16x8*>(gb);
        }
        __syncthreads();
        #pragma unroll
        for (int s = 0; s < 2; s++) {
            const int swz = (s * 64 + lg * 16) ^ ((lr & 7) << 4);
            bf16x8 af[4], bfr[4];
            #pragma unroll
            for (int mi = 0; mi < 4; mi++)
                af[mi] = *reinterpret_cast<const bf16x8*>(Al + (wr * 64 + mi * 16 + lr) * 128 + swz);
            #pragma unroll
            for (int ni = 0; ni < 4; ni++)
                bfr[ni] = *reinterpret_cast<const bf16x8*>(Bl + (wc * 64 + ni * 16 + lr) * 128 + swz);
            #pragma unroll
            for (int mi = 0; mi < 4; mi++)
                #pragma unroll
                for (int ni = 0; ni < 4; ni++)
                    acc[mi][ni] = MFMA(af[mi], bfr[ni], acc[mi][ni]);
        }
    }

    // epilogue
    #pragma unroll
    for (int mi = 0; mi < 4; mi++) {
        #pragma unroll
        for (int ni = 0; ni < 4; ni++) {
            int nn = n0 + wc * 64 + ni * 16 + lr;
            #pragma unroll
            for (int r = 0; r < 4; r++) {
                int mm = m0 + wr * 64 + mi * 16 + lg * 4 + r;
                float v = acc[mi][ni][r];
                if (MODE == 0) {
                    if (nn < 2048) {
                        Cb[(size_t)mm * NQKV + nn] = f2bf(v);
                    } else {
                        int b = mm >> 11, sIdx = mm & 2047;
                        int hd = nn - 2048;
                        vT[(((size_t)(b * HH + (hd >> 6)) * DH) + (hd & 63)) * SS + sIdx] = f2bf(v);
                    }
                } else if (MODE == 1) {
                    Cf[(size_t)mm * N + nn] = v + bias[nn] + res[(size_t)mm * N + nn];
                } else {
                    float u = v + bias[nn];
                    float gl = 0.5f * u * (1.0f + erff(u * 0.70710678118654752f));
                    Cb[(size_t)mm * N + nn] = f2bf(gl);
                }
            }
        }
    }
}

// ---------------- flash attention, swapped-QK 32x32: 1 wave = 32 q rows ----------------
// S^T[kv][q] = K·Q^T via mfma_32x32x16 (A=K, B=Q^T). Lane holds 16 kv-scores of ONE
// q row (col=lane&31) -> softmax fully in-register (one shfl_xor(32) per reduce).
// PV: O^T[d][q] = V^T·P, A=V^T from vT[b][h][d][s] (contiguous), B=P built in-register
// from bf16-packed exp values via 2 shfl_xor(32) + selects per k-slice.
__global__ __launch_bounds__(256)
void k_attn(const u16* __restrict__ qkv, const u16* __restrict__ vT,
            u16* __restrict__ out) {
    const int w = threadIdx.x >> 6, l = threadIdx.x & 63;
    const int q = l & 31, hi = l >> 5;
    const int task = blockIdx.x * 4 + w;     // 0..2047
    const int bh = task >> 6;                // 0..31  (64 q-tiles per head-seq)
    const int q32 = task & 63;
    const int b = bh >> 4, h = bh & 15;
    const size_t rowbase = (size_t)b * SS;
    const int q0 = q32 * 32;

    // Q B-fragments: B[k=dk][n=q]: lane needs Q[q0+q][h*64 + ks*16 + hi*8 + j]
    const u16* qrow = qkv + (rowbase + q0 + q) * NQKV + h * DH + hi * 8;
    bf16x8 qf[4];
    #pragma unroll
    for (int ks = 0; ks < 4; ks++)
        qf[ks] = *reinterpret_cast<const bf16x8*>(qrow + ks * 16);

    f32x16 o0 = zero16(), o1 = zero16();     // O^T[d][q], d-tiles 0/1
    float mQ = -1e30f, lQ = 0.f;

    const u16* kbase = qkv + rowbase * NQKV + 1024 + h * DH;
    const u16* vbase = vT + (size_t)bh * DH * SS;

    for (int kv0 = 0; kv0 < SS; kv0 += 32) {
        // K A-fragments: A[m=kv][k=dk]: row kv0+(l&31), cols ks*16+hi*8
        const u16* kp = kbase + (size_t)(kv0 + q) * NQKV + hi * 8;
        f32x16 st = zero16();
        st = MFMA32(*reinterpret_cast<const bf16x8*>(kp),      qf[0], st);
        st = MFMA32(*reinterpret_cast<const bf16x8*>(kp + 16), qf[1], st);
        st = MFMA32(*reinterpret_cast<const bf16x8*>(kp + 32), qf[2], st);
        st = MFMA32(*reinterpret_cast<const bf16x8*>(kp + 48), qf[3], st);

        f32x16 sc = st * 0.125f;
        // tile max over this lane's 16 kv + the partner half
        float tm = sc[0];
        #pragma unroll
        for (int i = 1; i < 16; i++) tm = fmaxf(tm, sc[i]);
        tm = fmaxf(tm, __shfl_xor(tm, 32));

        // defer-max (T13): rescale only when max grew by > 8
        if (!__all(tm - mQ <= 8.f)) {
            float mn = fmaxf(mQ, tm);
            float scale = __expf(mQ - mn);
            lQ *= scale;
            o0 *= scale;
            o1 *= scale;
            mQ = mn;
        }

        f32x16 p;
        #pragma unroll
        for (int i = 0; i < 16; i++) p[i] = __expf(sc[i] - mQ);
        float ts = p[0];
        #pragma unroll
        for (int i = 1; i < 16; i++) ts += p[i];
        ts += __shfl_xor(ts, 32);
        lQ += ts;

        // pack P to bf16 words: w[m] covers regs 2m, 2m+1
        union W { unsigned int u; __bf16 h[2]; };
        W pw[8];
        #pragma unroll
        for (int m = 0; m < 8; m++) {
            pw[m].h[0] = (__bf16)p[2 * m];
            pw[m].h[1] = (__bf16)p[2 * m + 1];
        }

        // build P B-fragments B[k=kv][n=q] for kk=0,1 (kv slices of 16)
        // reg r of lane(hi') holds kv=(r&3)+8*(r>>2)+4*hi'; frag j0-3 from hi'=0 lane,
        // j4-7 from hi'=1 lane; receiver hi needs word-block 4kk+2hi from BOTH lanes.
        bf16x8 pf[2];
        #pragma unroll
        for (int kk = 0; kk < 2; kk++) {
            unsigned int a0 = pw[4 * kk + 0].u, a1 = pw[4 * kk + 1].u;
            unsigned int b0 = pw[4 * kk + 2].u, b1 = pw[4 * kk + 3].u;
            unsigned int own0 = hi ? b0 : a0, own1 = hi ? b1 : a1;
            unsigned int snd0 = hi ? a0 : b0, snd1 = hi ? a1 : b1;
            unsigned int r0 = __shfl_xor(snd0, 32), r1 = __shfl_xor(snd1, 32);
            union F { unsigned int u[4]; bf16x8 v; } f;
            f.u[0] = hi ? r0 : own0;
            f.u[1] = hi ? r1 : own1;
            f.u[2] = hi ? own0 : r0;
            f.u[3] = hi ? own1 : r1;
            pf[kk] = f.v;
        }

        // PV: A=V^T[d][kv] from vT (contiguous 16B), accumulate O^T
        #pragma unroll
        for (int kk = 0; kk < 2; kk++) {
            const u16* vp = vbase + (size_t)q * SS + kv0 + kk * 16 + hi * 8;
            o0 = MFMA32(*reinterpret_cast<const bf16x8*>(vp), pf[kk], o0);
            o1 = MFMA32(*reinterpret_cast<const bf16x8*>(vp + 32 * SS), pf[kk], o1);
        }
    }

    // epilogue: lane q=l&31; reg r -> d = dt*32 + (r&3) + 8*(r>>2) + 4*hi
    float invl = 1.0f / lQ;
    u16* orow = out + (rowbase + q0 + q) * DD + h * DH + hi * 4;
    #pragma unroll
    for (int a = 0; a < 4; a++) {
        u16x4 s0v, s1v;
        #pragma unroll
        for (int i = 0; i < 4; i++) {
            s0v[i] = f2bf(o0[4 * a + i] * invl);
            s1v[i] = f2bf(o1[4 * a + i] * invl);
        }
        *reinterpret_cast<u16x4*>(orow + 8 * a)      = s0v;
        *reinterpret_cast<u16x4*>(orow + 32 + 8 * a) = s1v;
    }
}

extern "C" void kernel_launch(void* const* d_in, const int* in_sizes, int n_in,
                              void* d_out, int out_size, void* d_ws, size_t ws_size,
                              hipStream_t stream) {
    (void)in_sizes; (void)n_in; (void)out_size; (void)ws_size;
    const float* x     = (const float*)d_in[0];
    const float* w_qkv = (const float*)d_in[1];
    const float* w_out = (const float*)d_in[2];
    const float* b_out = (const float*)d_in[3];
    const float* g1    = (const float*)d_in[4];
    const float* be1   = (const float*)d_in[5];
    const float* g2    = (const float*)d_in[6];
    const float* be2   = (const float*)d_in[7];
    const float* w_ff1 = (const float*)d_in[8];
    const float* b_ff1 = (const float*)d_in[9];
    const float* w_ff2 = (const float*)d_in[10];
    const float* b_ff2 = (const float*)d_in[11];

    char* ws = (char*)d_ws;
    u16*   W  = (u16*)(ws);                  //  8.39 MB  (weight^T scratch, reused)
    u16*   Hb = (u16*)(ws + 8388608);        //  8.39 MB  (LN output bf16)
    u16*   QF = (u16*)(ws + 16777216);       // 33.55 MB  (qkv, later ffn act)
    u16*   VT = (u16*)(ws + 50331648);       //  8.39 MB  (v transposed)
    u16*   AO = (u16*)(ws + 58720256);       //  8.39 MB  (attn out bf16)
    float* X1 = (float*)(ws + 67108864);     // 16.78 MB  (post-attn residual fp32)
    float* OUT = (float*)d_out;

    // LN1: x -> Hb
    k_layernorm<<<NTOK, 256, 0, stream>>>(x, g1, be1, Hb);
    // w_qkv^T
    k_transpose<<<dim3(3072 / 32, 1024 / 32), dim3(32, 8), 0, stream>>>(w_qkv, W, 1024, 3072);
    // qkv = Hb @ w_qkv   (v written transposed to VT)
    k_gemm<0><<<dim3(3072 / 128, 4096 / 128), 256, 0, stream>>>(
        Hb, W, nullptr, QF, nullptr, nullptr, VT, NTOK, NQKV, 1024);
    // attention (2048 independent waves, 4 per block)
    k_attn<<<512, 256, 0, stream>>>(QF, VT, AO);
    // w_out^T
    k_transpose<<<dim3(1024 / 32, 1024 / 32), dim3(32, 8), 0, stream>>>(w_out, W, 1024, 1024);
    // X1 = x + AO @ w_out + b_out
    k_gemm<1><<<dim3(1024 / 128, 4096 / 128), 256, 0, stream>>>(
        AO, W, X1, nullptr, b_out, x, nullptr, NTOK, 1024, 1024);
    // LN2: X1 -> Hb
    k_layernorm<<<NTOK, 256, 0, stream>>>(X1, g2, be2, Hb);
    // w_ff1^T
    k_transpose<<<dim3(4096 / 32, 1024 / 32), dim3(32, 8), 0, stream>>>(w_ff1, W, 1024, 4096);
    // FFA = gelu(Hb @ w_ff1 + b_ff1)  (into QF region)
    k_gemm<2><<<dim3(4096 / 128, 4096 / 128), 256, 0, stream>>>(
        Hb, W, nullptr, QF, b_ff1, nullptr, nullptr, NTOK, 4096, 1024);
    // w_ff2^T
    k_transpose<<<dim3(1024 / 32, 4096 / 32), dim3(32, 8), 0, stream>>>(w_ff2, W, 4096, 1024);
    // OUT = X1 + FFA @ w_ff2 + b_ff2
    k_gemm<1><<<dim3(1024 / 128, 4096 / 128), 256, 0, stream>>>(
        QF, W, OUT, nullptr, b_ff2, X1, nullptr, NTOK, 1024, 4096);
}